// Round 6
// baseline (230.262 us; speedup 1.0000x reference)
//
#include <hip/hip_runtime.h>
#include <hip/hip_bf16.h>
#include <stdint.h>

// Per-edge MLP  out = relu(relu([h[src],h[dst]] @ W1.T + b1) @ W2.T + b2) @ W3.T + b3
// N=100000, H=128, E=1.6M, layers 256->64->32->6, fp32 in/out.
//
// Pipeline (2 dispatches, no weight-prep kernel -- all B-fragments load
// directly from W1/W2/W3: each lane's 8 k-values are contiguous floats):
//  1) node_gemm (MFMA): pre[n] = [h@W1a.T + b1 , h@W1b.T]  bf16, 25.6 MB, L3-resident
//  2) edge_mlp  (MFMA): 128 edges/wave; per 16-edge subtile layer2 = 2x2 MFMAs
//     (y built in-lane from gather: gather layout == A-frag layout), z relu'd
//     bf16 into a wave-private LDS slab in layer-3 A-frag order, layer3 = 1 MFMA
//     (W3 cols 6..15 zeroed). Gathers double-buffered one subtile ahead.
// MFMA 16x16x32_bf16 layouts (m89/m91-verified):
//   A[m=lane&15][k=(lane>>4)*8+j], B[k=(lane>>4)*8+j][n=lane&15],
//   C/D: col=lane&15, row=(lane>>4)*4+reg.

#define H 128

typedef short bf16x8 __attribute__((ext_vector_type(8)));
typedef float f32x4  __attribute__((ext_vector_type(4)));

__device__ __forceinline__ uint16_t f2bf(float f) {           // RNE fp32->bf16
    uint32_t u = __float_as_uint(f);
    return (uint16_t)((u + 0x7fffu + ((u >> 16) & 1u)) >> 16);
}
__device__ __forceinline__ float bf_lo(uint32_t u) { return __uint_as_float(u << 16); }
__device__ __forceinline__ float bf_hi(uint32_t u) { return __uint_as_float(u & 0xffff0000u); }
__device__ __forceinline__ uint32_t pk_bf16(float lo, float hi) {   // RNE pair pack
    __hip_bfloat162 v = __float22bfloat162_rn(float2{lo, hi});
    return *reinterpret_cast<uint32_t*>(&v);
}
__device__ __forceinline__ bf16x8 pack_frag(float4 lo, float4 hi) {
    union { bf16x8 v; uint32_t u[4]; } A;
    A.u[0] = pk_bf16(lo.x, lo.y);
    A.u[1] = pk_bf16(lo.z, lo.w);
    A.u[2] = pk_bf16(hi.x, hi.y);
    A.u[3] = pk_bf16(hi.z, hi.w);
    return A.v;
}

// ---------------- per-node precompute: pre = h @ concat-W1 (+b1), MFMA ------
// Block = 4 waves = 64 nodes. Per wave: M=16 nodes, N=128 (8 ntiles), K=128.
// B-frag (kt,nt) loads directly from W1: n=nt*16+m, k0=kt*32+quad*8;
//   n<64 -> W1[n][k0..k0+7], else W1[n-64][128+k0..]  (contiguous floats).
__global__ void __launch_bounds__(256) node_gemm(
    const float* __restrict__ h,
    const float* __restrict__ W1,
    const float* __restrict__ b1,
    uint16_t* __restrict__ pre, int N)
{
    const int wave = threadIdx.x >> 6;
    const int lane = threadIdx.x & 63;
    const int n0 = (blockIdx.x * 4 + wave) * 16;
    if (n0 >= N) return;

    const int m    = lane & 15;
    const int quad = lane >> 4;

    int arow = n0 + m; if (arow >= N) arow = N - 1;   // clamp (stores guarded)
    const float* hrow = h + (size_t)arow * H + quad * 8;

    // A fragments: 4 ktiles, fp32 -> bf16 RNE in-register.
    bf16x8 afr[4];
#pragma unroll
    for (int kt = 0; kt < 4; kt++) {
        float4 lo = *(const float4*)(hrow + kt * 32);
        float4 hi = *(const float4*)(hrow + kt * 32 + 4);
        afr[kt] = pack_frag(lo, hi);
    }

    // b1 per lane for nt<4 (ncol = nt*16+m < 64).
    float vb1[4];
#pragma unroll
    for (int nt = 0; nt < 4; nt++) vb1[nt] = b1[nt * 16 + m];

#pragma unroll
    for (int nt = 0; nt < 8; nt++) {
        const int n = nt * 16 + m;
        const float* wrow = (n < 64) ? (W1 + (size_t)n * 256)
                                     : (W1 + (size_t)(n - 64) * 256 + 128);
        f32x4 acc = {0.f, 0.f, 0.f, 0.f};
#pragma unroll
        for (int kt = 0; kt < 4; kt++) {
            const float* wp = wrow + kt * 32 + quad * 8;   // L1/L2-hot (W1 = 64 KB)
            float4 lo = *(const float4*)wp;
            float4 hi = *(const float4*)(wp + 4);
            bf16x8 bfr = pack_frag(lo, hi);
            acc = __builtin_amdgcn_mfma_f32_16x16x32_bf16(afr[kt], bfr, acc, 0, 0, 0);
        }
        const float bv = (nt < 4) ? vb1[nt] : 0.f;
#pragma unroll
        for (int r = 0; r < 4; r++) {
            const int node = n0 + quad * 4 + r;
            if (node < N)
                pre[(size_t)node * H + n] = f2bf(acc[r] + bv);
        }
    }
}

// ---------------- per-edge MLP: MFMA layers 2+3, 128 edges/wave --------------
__global__ void __launch_bounds__(256, 2) edge_mlp(
    const uint16_t* __restrict__ pre,
    const int* __restrict__ src, const int* __restrict__ dst,
    const float* __restrict__ W2, const float* __restrict__ b2,
    const float* __restrict__ W3, const float* __restrict__ b3,
    float* __restrict__ out, long E)
{
    __shared__ uint16_t zbuf[4][64 * 40];   // wave-private 64-edge z slab, stride 40 halves

    const int wave = threadIdx.x >> 6;
    const int lane = threadIdx.x & 63;
    const int m15  = lane & 15;
    const int quad = lane >> 4;
    uint16_t* zw = &zbuf[wave][0];

    // Layer-2 B-frags direct from W2 (32x64): frag f=kt*2+nt,
    //   n=nt*16+m15 (<32), k0=kt*32+quad*8 -> W2[n][k0..k0+7] contiguous.
    bf16x8 bL2[4];
#pragma unroll
    for (int f = 0; f < 4; f++) {
        const int kt = f >> 1, nt = f & 1;
        const float* wp = W2 + (size_t)(nt * 16 + m15) * 64 + kt * 32 + quad * 8;
        bL2[f] = pack_frag(*(const float4*)wp, *(const float4*)(wp + 4));
    }
    // Layer-3 B-frag from W3 (6x32), cols n>=6 zeroed.
    bf16x8 bL3;
    {
        const int n3 = (m15 < 6) ? m15 : 0;                // clamp to avoid OOB
        const float* wp = W3 + (size_t)n3 * 32 + quad * 8;
        union { bf16x8 v; uint32_t u[4]; } A;
        float4 lo = *(const float4*)wp, hi = *(const float4*)(wp + 4);
        A.u[0] = pk_bf16(lo.x, lo.y); A.u[1] = pk_bf16(lo.z, lo.w);
        A.u[2] = pk_bf16(hi.x, hi.y); A.u[3] = pk_bf16(hi.z, hi.w);
        if (m15 >= 6) { A.u[0] = A.u[1] = A.u[2] = A.u[3] = 0; }
        bL3 = A.v;
    }
    const float vb2a = b2[m15];
    const float vb2b = b2[16 + m15];
    const float vb3  = (m15 < 6) ? b3[m15] : 0.f;

    const long base = (long)(blockIdx.x * 4 + wave) * 128;
    if (base >= E) return;

    // Per-subtile edge indices for this lane (A row m15 of subtile st).
    int sidx[8], didx[8];
#pragma unroll
    for (int st = 0; st < 8; st++) {
        long e = base + st * 16 + m15;
        if (e >= E) e = E - 1;                       // tail clamp (stores guarded)
        sidx[st] = src[e]; didx[st] = dst[e];
    }

    // Double-buffered gather: fetch subtile st+1 while computing st.
    uint4 ga[2][2], gb[2][2];
    {
        const uint16_t* pa = pre + (size_t)sidx[0] * H;
        const uint16_t* pb = pre + (size_t)didx[0] * H + 64;
        ga[0][0] = *(const uint4*)(pa + quad * 8);
        ga[0][1] = *(const uint4*)(pa + 32 + quad * 8);
        gb[0][0] = *(const uint4*)(pb + quad * 8);
        gb[0][1] = *(const uint4*)(pb + 32 + quad * 8);
    }

#pragma unroll
    for (int st = 0; st < 8; st++) {
        const int cur = st & 1;
        if (st < 7) {
            const int nb = cur ^ 1;
            const uint16_t* pa = pre + (size_t)sidx[st + 1] * H;
            const uint16_t* pb = pre + (size_t)didx[st + 1] * H + 64;
            ga[nb][0] = *(const uint4*)(pa + quad * 8);
            ga[nb][1] = *(const uint4*)(pa + 32 + quad * 8);
            gb[nb][0] = *(const uint4*)(pb + quad * 8);
            gb[nb][1] = *(const uint4*)(pb + 32 + quad * 8);
        }

        // y = relu(pa + pb) in-lane -> layer-2 A-frags (2 ktiles).
        bf16x8 afr[2];
#pragma unroll
        for (int kt = 0; kt < 2; kt++) {
            uint4 ua = ga[cur][kt];
            uint4 ub = gb[cur][kt];
            float y0 = fmaxf(bf_lo(ua.x) + bf_lo(ub.x), 0.f);
            float y1 = fmaxf(bf_hi(ua.x) + bf_hi(ub.x), 0.f);
            float y2 = fmaxf(bf_lo(ua.y) + bf_lo(ub.y), 0.f);
            float y3 = fmaxf(bf_hi(ua.y) + bf_hi(ub.y), 0.f);
            float y4 = fmaxf(bf_lo(ua.z) + bf_lo(ub.z), 0.f);
            float y5 = fmaxf(bf_hi(ua.z) + bf_hi(ub.z), 0.f);
            float y6 = fmaxf(bf_lo(ua.w) + bf_lo(ub.w), 0.f);
            float y7 = fmaxf(bf_hi(ua.w) + bf_hi(ub.w), 0.f);
            union { bf16x8 v; uint32_t u[4]; } A;
            A.u[0] = pk_bf16(y0, y1);
            A.u[1] = pk_bf16(y2, y3);
            A.u[2] = pk_bf16(y4, y5);
            A.u[3] = pk_bf16(y6, y7);
            afr[kt] = A.v;
        }

        // Layer 2: 2 ntiles x 2 chained MFMAs; z -> LDS slot (st&3).
#pragma unroll
        for (int nt = 0; nt < 2; nt++) {
            f32x4 acc = {0.f, 0.f, 0.f, 0.f};
            acc = __builtin_amdgcn_mfma_f32_16x16x32_bf16(afr[0], bL2[nt],     acc, 0, 0, 0);
            acc = __builtin_amdgcn_mfma_f32_16x16x32_bf16(afr[1], bL2[2 + nt], acc, 0, 0, 0);
            const float vb2 = nt ? vb2b : vb2a;
#pragma unroll
            for (int r = 0; r < 4; r++) {
                float z = fmaxf(acc[r] + vb2, 0.f);
                int el = (st & 3) * 16 + quad * 4 + r;      // C row = edge-in-subgroup
                zw[el * 40 + nt * 16 + m15] = f2bf(z);
            }
        }

        // Layer 3 once per 64-edge group (subtiles g*4 .. g*4+3).
        if ((st & 3) == 3) {
            const long gbase = base + (long)(st >> 2) * 64;
#pragma unroll
            for (int s2 = 0; s2 < 4; s2++) {
                bf16x8 a3 = *(const bf16x8*)(zw + (s2 * 16 + m15) * 40 + quad * 8);
                f32x4 o = {0.f, 0.f, 0.f, 0.f};
                o = __builtin_amdgcn_mfma_f32_16x16x32_bf16(a3, bL3, o, 0, 0, 0);
                if (m15 < 6) {
#pragma unroll
                    for (int r = 0; r < 4; r++) {
                        long e = gbase + s2 * 16 + quad * 4 + r;
                        if (e < E) out[e * 6 + m15] = o[r] + vb3;
                    }
                }
            }
        }
    }
}

extern "C" void kernel_launch(void* const* d_in, const int* in_sizes, int n_in,
                              void* d_out, int out_size, void* d_ws, size_t ws_size,
                              hipStream_t stream) {
    const float* h   = (const float*)d_in[0];
    const int*   src = (const int*)d_in[1];
    const int*   dst = (const int*)d_in[2];
    const float* W1  = (const float*)d_in[3];
    const float* b1  = (const float*)d_in[4];
    const float* W2  = (const float*)d_in[5];
    const float* b2  = (const float*)d_in[6];
    const float* W3  = (const float*)d_in[7];
    const float* b3  = (const float*)d_in[8];

    const int  N = in_sizes[0] / H;     // 100000
    const long E = in_sizes[1];         // 1600000

    uint16_t* pre = (uint16_t*)d_ws;    // N*128*2 = 25.6 MB (bf16)

    node_gemm<<<(N + 63) / 64, 256, 0, stream>>>(h, W1, b1, pre, N);
    const int eblocks = (int)((E + 511) / 512);     // 4 waves x 128 edges per block
    edge_mlp<<<eblocks, 256, 0, stream>>>(pre, src, dst, W2, b2, W3, b3,
                                          (float*)d_out, E);
}

// Round 8
// 182.997 us; speedup vs baseline: 1.2583x; 1.2583x over previous
//
#include <hip/hip_runtime.h>
#include <hip/hip_bf16.h>
#include <stdint.h>

// Per-edge MLP  out = relu(relu([h[src],h[dst]] @ W1.T + b1) @ W2.T + b2) @ W3.T + b3
// N=100000, H=128, E=1.6M, layers 256->64->32->6, fp32 in/out.
//
// Pipeline:
//  0) prep_weights: W1 -> Bfrag (node_gemm B-frag order, bf16, 32KB),
//     W2/W3 -> EFrag (edge_mlp B-frags, bf16, 5KB). Kept as its own tiny
//     dispatch: R6 showed inlining the repack into node_gemm's K-loop costs
//     ~30us there vs ~2us here.
//  1) node_gemm (MFMA): pre[n] = [h@W1a.T + b1 , h@W1b.T] bf16 (25.6MB, L3-res).
//     32 nodes/wave: 2 M-tiles share each B-frag load.
//  2) edge_mlp (MFMA): 64 edges/wave; all 16 gathers issued upfront (flat regs,
//     32-bit offsets) so vmcnt pipelining hides L2/L3 latency; y built with
//     packed-bf16 __hadd2/__hmax2 (A-frag = bit-reinterpret, no repack);
//     z relu'd bf16 into wave-private LDS slab (layer-3 A-frag order);
//     layer3 = 1 MFMA/subtile, W3 cols 6..15 zeroed.
// MFMA 16x16x32_bf16 layouts (m89/m91-verified):
//   A[m=lane&15][k=(lane>>4)*8+j], B[k=(lane>>4)*8+j][n=lane&15],
//   C/D: col=lane&15, row=(lane>>4)*4+reg.
//
// R8: compile fix only vs R7 -- ROCm 7.2 has no __float2bfloat162_rn(float);
// packed bf16 zero built by bit-reinterpreting 0u (bf16 +0 == all-zero bits).

#define H 128

typedef short bf16x8 __attribute__((ext_vector_type(8)));
typedef float f32x4  __attribute__((ext_vector_type(4)));

__device__ __forceinline__ uint16_t f2bf(float f) {           // RNE fp32->bf16
    uint32_t u = __float_as_uint(f);
    return (uint16_t)((u + 0x7fffu + ((u >> 16) & 1u)) >> 16);
}
__device__ __forceinline__ uint32_t pk_bf16(float lo, float hi) {   // RNE pair pack
    __hip_bfloat162 v = __float22bfloat162_rn(float2{lo, hi});
    return *reinterpret_cast<uint32_t*>(&v);
}
// relu(a+b) on a packed bf16 pair (maps to packed VALU if gfx950 provides it)
__device__ __forceinline__ uint32_t bfadd2_relu(uint32_t a, uint32_t b) {
    __hip_bfloat162 x = *reinterpret_cast<__hip_bfloat162*>(&a);
    __hip_bfloat162 y = *reinterpret_cast<__hip_bfloat162*>(&b);
    __hip_bfloat162 s = __hadd2(x, y);
    uint32_t zu = 0u;                                  // packed bf16 {+0, +0}
    __hip_bfloat162 zero = *reinterpret_cast<__hip_bfloat162*>(&zu);
    __hip_bfloat162 r = __hmax2(s, zero);
    return *reinterpret_cast<uint32_t*>(&r);
}

// ---------------- weight prep ------------------------------------------------
// Bfrag (node_gemm): concat-W1 in B-frag order, 4 ktiles x 8 ntiles (32 KB):
//   i = ((kt*8+nt)*64+lane)*8+j -> B[k=kt*32+(lane>>4)*8+j][n=nt*16+(lane&15)],
//   B[k][n] = n<64 ? W1[n][k] : W1[n-64][128+k]
// EFrag (edge_mlp): 5 frags x 64 lanes x 8 bf16 (5 KB):
//   f=kt*2+nt (f<4): layer2 B[k=kt*32+(lane>>4)*8+j][n=nt*16+(lane&15)] = W2[n][k]
//   f=4:             layer3 B[k=(lane>>4)*8+j][n=lane&15] = (n<6)? W3[n][k] : 0
__global__ void prep_weights(const float* __restrict__ W1,
                             const float* __restrict__ W2,
                             const float* __restrict__ W3,
                             uint16_t* __restrict__ Bfrag,
                             uint16_t* __restrict__ EFrag)
{
    int t = blockIdx.x * blockDim.x + threadIdx.x;
    int stride = gridDim.x * blockDim.x;
    for (int i = t; i < 4 * 8 * 64 * 8; i += stride) {
        int j    = i & 7;
        int lane = (i >> 3) & 63;
        int nt   = (i >> 9) & 7;
        int kt   = (i >> 12);
        int k = kt * 32 + (lane >> 4) * 8 + j;
        int n = nt * 16 + (lane & 15);
        float v = (n < 64) ? W1[n * 256 + k] : W1[(n - 64) * 256 + 128 + k];
        Bfrag[i] = f2bf(v);
    }
    for (int i = t; i < 5 * 64 * 8; i += stride) {
        int j    = i & 7;
        int lane = (i >> 3) & 63;
        int f    = i >> 9;
        uint16_t v;
        if (f < 4) {
            int kt = f >> 1, nt = f & 1;
            int k = kt * 32 + (lane >> 4) * 8 + j;
            int n = nt * 16 + (lane & 15);
            v = f2bf(W2[n * 64 + k]);
        } else {
            int k = (lane >> 4) * 8 + j;
            int n = lane & 15;
            v = (n < 6) ? f2bf(W3[n * 32 + k]) : (uint16_t)0;
        }
        EFrag[i] = v;
    }
}

// ---------------- per-node precompute: pre = h @ concat-W1 (+b1), MFMA ------
// Block = 4 waves = 128 nodes. Per wave: 2 M-tiles (32 nodes) x 8 ntiles x
// 4 ktiles; each B-frag load feeds 2 MFMAs.
__global__ void __launch_bounds__(256) node_gemm(
    const float* __restrict__ h,
    const uint16_t* __restrict__ Bfrag,
    const float* __restrict__ b1,
    uint16_t* __restrict__ pre, int N)
{
    const int wave = threadIdx.x >> 6;
    const int lane = threadIdx.x & 63;
    const int n0 = (blockIdx.x * 4 + wave) * 32;
    if (n0 >= N) return;

    const int m    = lane & 15;
    const int quad = lane >> 4;

    // A fragments for both M-tiles (fp32 -> bf16 RNE in-register).
    bf16x8 afr[2][4];
#pragma unroll
    for (int mt = 0; mt < 2; mt++) {
        int arow = n0 + mt * 16 + m; if (arow >= N) arow = N - 1;  // stores guarded
        const float* hrow = h + (size_t)arow * H + quad * 8;
#pragma unroll
        for (int kt = 0; kt < 4; kt++) {
            float4 lo = *(const float4*)(hrow + kt * 32);
            float4 hi = *(const float4*)(hrow + kt * 32 + 4);
            union { bf16x8 v; uint32_t u[4]; } A;
            A.u[0] = pk_bf16(lo.x, lo.y); A.u[1] = pk_bf16(lo.z, lo.w);
            A.u[2] = pk_bf16(hi.x, hi.y); A.u[3] = pk_bf16(hi.z, hi.w);
            afr[mt][kt] = A.v;
        }
    }

#pragma unroll
    for (int nt = 0; nt < 8; nt++) {
        const int n = nt * 16 + m;
        f32x4 acc0 = {0.f, 0.f, 0.f, 0.f};
        f32x4 acc1 = {0.f, 0.f, 0.f, 0.f};
#pragma unroll
        for (int kt = 0; kt < 4; kt++) {
            bf16x8 bfr = *(const bf16x8*)(Bfrag + ((size_t)(kt * 8 + nt) * 64 + lane) * 8);
            acc0 = __builtin_amdgcn_mfma_f32_16x16x32_bf16(afr[0][kt], bfr, acc0, 0, 0, 0);
            acc1 = __builtin_amdgcn_mfma_f32_16x16x32_bf16(afr[1][kt], bfr, acc1, 0, 0, 0);
        }
        const float bv = (n < 64) ? b1[n] : 0.f;
#pragma unroll
        for (int r = 0; r < 4; r++) {
            const int node0 = n0 + quad * 4 + r;
            if (node0 < N) pre[(size_t)node0 * H + n] = f2bf(acc0[r] + bv);
            const int node1 = n0 + 16 + quad * 4 + r;
            if (node1 < N) pre[(size_t)node1 * H + n] = f2bf(acc1[r] + bv);
        }
    }
}

// ---------------- per-edge MLP: MFMA layers 2+3, 64 edges/wave ---------------
__global__ void __launch_bounds__(256) edge_mlp(
    const uint16_t* __restrict__ pre,
    const int* __restrict__ src, const int* __restrict__ dst,
    const uint16_t* __restrict__ EFrag,
    const float* __restrict__ b2, const float* __restrict__ b3,
    float* __restrict__ out, long E)
{
    __shared__ uint16_t zbuf[4][64 * 40];   // wave-private z slab, stride 40 halves

    const int wave = threadIdx.x >> 6;
    const int lane = threadIdx.x & 63;
    const int m15  = lane & 15;
    const int quad = lane >> 4;
    uint16_t* zw = &zbuf[wave][0];

    // Preload B-fragments (L2-hot) and biases.
    bf16x8 bL2[4], bL3;
#pragma unroll
    for (int f = 0; f < 4; f++) bL2[f] = *(const bf16x8*)(EFrag + (f * 64 + lane) * 8);
    bL3 = *(const bf16x8*)(EFrag + (4 * 64 + lane) * 8);
    const float vb2a = b2[m15];
    const float vb2b = b2[16 + m15];
    const float vb3  = (m15 < 6) ? b3[m15] : 0.f;

    const long e0 = (long)(blockIdx.x * 4 + wave) * 64;
    if (e0 >= E) return;

    // ---- issue ALL 16 gathers upfront: flat regs, 32-bit byte offsets -------
    // pre row = 256 B; lane reads 2x16B per side (halves [0,64) src / [64,128) dst).
    const char* preb = (const char*)pre;
    uint32_t oa0, oa1, oa2, oa3, ob0, ob1, ob2, ob3;
    {
        long ea = e0 + m15;           // subtile st uses edge e0+st*16+m15
        long eb = (ea + 16 < E) ? ea + 16 : E - 1;
        long ec = (ea + 32 < E) ? ea + 32 : E - 1;
        long ed = (ea + 48 < E) ? ea + 48 : E - 1;
        if (ea >= E) ea = E - 1;
        oa0 = (uint32_t)src[ea] * 256u + (uint32_t)quad * 16u;
        ob0 = (uint32_t)dst[ea] * 256u + 128u + (uint32_t)quad * 16u;
        oa1 = (uint32_t)src[eb] * 256u + (uint32_t)quad * 16u;
        ob1 = (uint32_t)dst[eb] * 256u + 128u + (uint32_t)quad * 16u;
        oa2 = (uint32_t)src[ec] * 256u + (uint32_t)quad * 16u;
        ob2 = (uint32_t)dst[ec] * 256u + 128u + (uint32_t)quad * 16u;
        oa3 = (uint32_t)src[ed] * 256u + (uint32_t)quad * 16u;
        ob3 = (uint32_t)dst[ed] * 256u + 128u + (uint32_t)quad * 16u;
    }
    uint4 a00 = *(const uint4*)(preb + oa0);
    uint4 a01 = *(const uint4*)(preb + oa0 + 64);
    uint4 b00 = *(const uint4*)(preb + ob0);
    uint4 b01 = *(const uint4*)(preb + ob0 + 64);
    uint4 a10 = *(const uint4*)(preb + oa1);
    uint4 a11 = *(const uint4*)(preb + oa1 + 64);
    uint4 b10 = *(const uint4*)(preb + ob1);
    uint4 b11 = *(const uint4*)(preb + ob1 + 64);
    uint4 a20 = *(const uint4*)(preb + oa2);
    uint4 a21 = *(const uint4*)(preb + oa2 + 64);
    uint4 b20 = *(const uint4*)(preb + ob2);
    uint4 b21 = *(const uint4*)(preb + ob2 + 64);
    uint4 a30 = *(const uint4*)(preb + oa3);
    uint4 a31 = *(const uint4*)(preb + oa3 + 64);
    uint4 b30 = *(const uint4*)(preb + ob3);
    uint4 b31 = *(const uint4*)(preb + ob3 + 64);

    // ---- layer 2 per subtile: packed-bf16 relu(a+b) -> A-frag -> 2x2 MFMA ---
#define DO_SUBTILE(ST, UA0, UB0, UA1, UB1)                                        \
    {                                                                             \
        union { bf16x8 v; uint32_t u[4]; } A0, A1;                                \
        A0.u[0] = bfadd2_relu(UA0.x, UB0.x);                                      \
        A0.u[1] = bfadd2_relu(UA0.y, UB0.y);                                      \
        A0.u[2] = bfadd2_relu(UA0.z, UB0.z);                                      \
        A0.u[3] = bfadd2_relu(UA0.w, UB0.w);                                      \
        A1.u[0] = bfadd2_relu(UA1.x, UB1.x);                                      \
        A1.u[1] = bfadd2_relu(UA1.y, UB1.y);                                      \
        A1.u[2] = bfadd2_relu(UA1.z, UB1.z);                                      \
        A1.u[3] = bfadd2_relu(UA1.w, UB1.w);                                      \
        _Pragma("unroll")                                                         \
        for (int nt = 0; nt < 2; nt++) {                                          \
            f32x4 acc = {0.f, 0.f, 0.f, 0.f};                                     \
            acc = __builtin_amdgcn_mfma_f32_16x16x32_bf16(A0.v, bL2[nt], acc, 0, 0, 0); \
            acc = __builtin_amdgcn_mfma_f32_16x16x32_bf16(A1.v, bL2[2 + nt], acc, 0, 0, 0); \
            const float vb2 = nt ? vb2b : vb2a;                                   \
            _Pragma("unroll")                                                     \
            for (int r = 0; r < 4; r++) {                                         \
                float z = fmaxf(acc[r] + vb2, 0.f);                               \
                zw[((ST) * 16 + quad * 4 + r) * 40 + nt * 16 + m15] = f2bf(z);    \
            }                                                                     \
        }                                                                         \
    }

    DO_SUBTILE(0, a00, b00, a01, b01)
    DO_SUBTILE(1, a10, b10, a11, b11)
    DO_SUBTILE(2, a20, b20, a21, b21)
    DO_SUBTILE(3, a30, b30, a31, b31)
#undef DO_SUBTILE

    // ---- layer 3: LDS A-frags -> 1 MFMA per subtile -------------------------
#pragma unroll
    for (int st = 0; st < 4; st++) {
        bf16x8 a3 = *(const bf16x8*)(zw + (st * 16 + m15) * 40 + quad * 8);
        f32x4 o = {0.f, 0.f, 0.f, 0.f};
        o = __builtin_amdgcn_mfma_f32_16x16x32_bf16(a3, bL3, o, 0, 0, 0);
        if (m15 < 6) {
#pragma unroll
            for (int r = 0; r < 4; r++) {
                long e = e0 + st * 16 + quad * 4 + r;
                if (e < E) out[e * 6 + m15] = o[r] + vb3;
            }
        }
    }
}

extern "C" void kernel_launch(void* const* d_in, const int* in_sizes, int n_in,
                              void* d_out, int out_size, void* d_ws, size_t ws_size,
                              hipStream_t stream) {
    const float* h   = (const float*)d_in[0];
    const int*   src = (const int*)d_in[1];
    const int*   dst = (const int*)d_in[2];
    const float* W1  = (const float*)d_in[3];
    const float* b1  = (const float*)d_in[4];
    const float* W2  = (const float*)d_in[5];
    const float* b2  = (const float*)d_in[6];
    const float* W3  = (const float*)d_in[7];
    const float* b3  = (const float*)d_in[8];

    const int  N = in_sizes[0] / H;     // 100000
    const long E = in_sizes[1];         // 1600000

    char* ws = (char*)d_ws;
    uint16_t* Bfrag = (uint16_t*)ws;                 // 32 KiB
    uint16_t* EFrag = (uint16_t*)(ws + 64 * 1024);   // 5 KiB
    uint16_t* pre   = (uint16_t*)(ws + 128 * 1024);  // N*128*2 = 25.6 MB (bf16)

    prep_weights<<<64, 256, 0, stream>>>(W1, W2, W3, Bfrag, EFrag);
    node_gemm<<<(N + 127) / 128, 256, 0, stream>>>(h, Bfrag, b1, pre, N);
    const int eblocks = (int)((E + 255) / 256);      // 4 waves x 64 edges per block
    edge_mlp<<<eblocks, 256, 0, stream>>>(pre, src, dst, EFrag, b2, b3,
                                          (float*)d_out, E);
}